// Round 1
// baseline (3350.380 us; speedup 1.0000x reference)
//
#include <hip/hip_runtime.h>

// CKY inside-outside (log semiring) for B=16, S=192.
//   inside:  c[i][j] = sp[i][j] + LSE_{k=i..j-1}( c[i][k] + c[k+1][j] ),  c[i][i]=sp[i][i]
//   Z[b] = c[0][L-1]
//   outside (stored as od = o + sp):
//     o[0][L-1] = 0
//     o[i][j] = LSE( o[i][p]+sp[i][p]+c[j+1][p] for p=j+1..L-1,
//                    o[a][j]+sp[a][j]+c[a][i-1] for a=0..i-1 )
//   marginal[i][j] = sigmoid(r[i][j]) * exp(o[i][j] + c[i][j] - Z)   (0 outside i<=j<L)
//
// One workgroup per batch. Chart / outside chart live in LDS with padded
// stride 193 (193 % 32 == 1 -> column reads are bank-conflict-free).
// 192*193*4 = 148224 B LDS -> 1 block/CU, 16 CUs busy.

#define SS 192
#define LD 193           // padded LDS row stride
#define BB 16
#define NT 1024          // 16 waves

__device__ __forceinline__ float softplusf(float x) {
  return fmaxf(x, 0.f) + log1pf(__expf(-fabsf(x)));
}

__global__ __launch_bounds__(NT) void cky_inside(const float* __restrict__ rules,
                                                 const int* __restrict__ lens,
                                                 float* __restrict__ chartG,
                                                 float* __restrict__ chartT,
                                                 float* __restrict__ spG,
                                                 float* __restrict__ outZ) {
  extern __shared__ float ch[];            // ch[i*LD + j]
  const int b = blockIdx.x;
  const int tid = threadIdx.x;
  const float* __restrict__ R = rules + (size_t)b * SS * SS;
  float* __restrict__ SPb = spG + (size_t)b * SS * SS;

  // diagonal
  for (int i = tid; i < SS; i += NT) {
    float sp = softplusf(R[i * SS + i]);
    ch[i * LD + i] = sp;
    SPb[i * SS + i] = sp;
  }
  __syncthreads();

  for (int w = 1; w < SS; ++w) {
    const int ncell = SS - w;
    const int nterm = w;
    const int Glog = (nterm <= 6) ? 0 : ((nterm <= 48) ? 3 : 6);
    const int G = 1 << Glog;
    const int grp = tid >> Glog;
    const int lane = tid & (G - 1);
    const int ngrp = NT >> Glog;
    for (int c = grp; c < ncell; c += ngrp) {
      const int i = c, j = c + w;
      float m = -1e30f, s = 0.f;       // online LSE state
      for (int k = i + lane; k < j; k += G) {
        float v = ch[i * LD + k] + ch[(k + 1) * LD + j];
        float nm = fmaxf(m, v);
        s = s * __expf(m - nm) + __expf(v - nm);
        m = nm;
      }
      for (int off = G >> 1; off > 0; off >>= 1) {
        float m2 = __shfl_xor(m, off);
        float s2 = __shfl_xor(s, off);
        float nm = fmaxf(m, m2);
        s = s * __expf(m - nm) + s2 * __expf(m2 - nm);
        m = nm;
      }
      if (lane == 0) {
        float sp = softplusf(R[i * SS + j]);
        SPb[i * SS + j] = sp;
        ch[i * LD + j] = sp + m + __logf(s);
      }
    }
    __syncthreads();
  }

  // dump chart (and transpose) to global for the outside pass; write Z
  float* __restrict__ Cb = chartG + (size_t)b * SS * SS;
  float* __restrict__ Tb = chartT + (size_t)b * SS * SS;
  for (int idx = tid; idx < SS * SS; idx += NT) {
    int i = idx / SS, j = idx - i * SS;
    float v = ch[i * LD + j];
    Cb[idx] = v;
    Tb[j * SS + i] = v;
  }
  if (tid == 0) {
    int L = lens[b];
    outZ[b] = ch[(L - 1)];               // ch[0*LD + (L-1)]
  }
}

__global__ __launch_bounds__(NT) void cky_outside(const float* __restrict__ rules,
                                                  const int* __restrict__ lens,
                                                  const float* __restrict__ chartG,
                                                  const float* __restrict__ chartT,
                                                  const float* __restrict__ spG,
                                                  float* __restrict__ marg) {
  extern __shared__ float od[];            // stores (o + sp) at [i*LD + j]
  const int b = blockIdx.x;
  const int tid = threadIdx.x;
  const int L = lens[b];
  const float* __restrict__ R  = rules  + (size_t)b * SS * SS;
  const float* __restrict__ C  = chartG + (size_t)b * SS * SS;
  const float* __restrict__ CT = chartT + (size_t)b * SS * SS;
  const float* __restrict__ SPb = spG   + (size_t)b * SS * SS;

  if (tid == 0) od[(L - 1)] = SPb[L - 1];  // root: o=0 -> store sp[0][L-1]
  __syncthreads();

  for (int w = L - 2; w >= 0; --w) {
    const int ncell = L - w;
    const int nterm = L - 1 - w;           // (L-1-j) left-parents + i right-parents
    const int Glog = (nterm <= 6) ? 0 : ((nterm <= 48) ? 3 : 6);
    const int G = 1 << Glog;
    const int grp = tid >> Glog;
    const int lane = tid & (G - 1);
    const int ngrp = NT >> Glog;
    for (int c = grp; c < ncell; c += ngrp) {
      const int i = c, j = c + w;
      const int nl = L - 1 - j;            // # left-parent terms
      float m = -1e30f, s = 0.f;
      for (int t = lane; t < nterm; t += G) {
        float v;
        if (t < nl) {                      // parent [i, p], we are left child
          int p = j + 1 + t;
          v = od[i * LD + p] + C[(j + 1) * SS + p];
        } else {                           // parent [a, j], we are right child
          int a = t - nl;
          v = od[a * LD + j] + CT[(i - 1) * SS + a];
        }
        float nm = fmaxf(m, v);
        s = s * __expf(m - nm) + __expf(v - nm);
        m = nm;
      }
      for (int off = G >> 1; off > 0; off >>= 1) {
        float m2 = __shfl_xor(m, off);
        float s2 = __shfl_xor(s, off);
        float nm = fmaxf(m, m2);
        s = s * __expf(m - nm) + s2 * __expf(m2 - nm);
        m = nm;
      }
      if (lane == 0) {
        od[i * LD + j] = SPb[i * SS + j] + m + __logf(s);
      }
    }
    __syncthreads();
  }

  // marginals
  const float Z = C[L - 1];                // c[0][L-1]
  float* __restrict__ Mb = marg + (size_t)b * SS * SS;
  for (int idx = tid; idx < SS * SS; idx += NT) {
    int i = idx / SS, j = idx - i * SS;
    float val = 0.f;
    if (i <= j && j < L) {
      float o = od[i * LD + j] - SPb[idx];
      float r = R[idx];
      float sig = 1.f / (1.f + __expf(-r));
      val = sig * __expf(o + C[idx] - Z);
    }
    Mb[idx] = val;
  }
}

extern "C" void kernel_launch(void* const* d_in, const int* in_sizes, int n_in,
                              void* d_out, int out_size, void* d_ws, size_t ws_size,
                              hipStream_t stream) {
  const float* rules = (const float*)d_in[0];   // (B,S,S,1) f32
  const int* lens = (const int*)d_in[1];        // (B,) i32
  float* outZ = (float*)d_out;                  // [0:16) = Z
  float* marg = (float*)d_out + BB;             // [16:16+B*S*S) = marginal

  float* chartG = (float*)d_ws;                                   // B*S*S
  float* chartT = chartG + (size_t)BB * SS * SS;                  // B*S*S
  float* spG    = chartT + (size_t)BB * SS * SS;                  // B*S*S

  const int smem = SS * LD * sizeof(float);     // 148224 B
  hipFuncSetAttribute(reinterpret_cast<const void*>(cky_inside),
                      hipFuncAttributeMaxDynamicSharedMemorySize, smem);
  hipFuncSetAttribute(reinterpret_cast<const void*>(cky_outside),
                      hipFuncAttributeMaxDynamicSharedMemorySize, smem);

  cky_inside<<<BB, NT, smem, stream>>>(rules, lens, chartG, chartT, spG, outZ);
  cky_outside<<<BB, NT, smem, stream>>>(rules, lens, chartG, chartT, spG, marg);
}

// Round 2
// 1620.421 us; speedup vs baseline: 2.0676x; 2.0676x over previous
//
#include <hip/hip_runtime.h>

// CKY inside-outside (log semiring), B=16, S=192.
// One workgroup per batch; chart in LDS, padded stride 193 (conflict-free cols).
// Per width w: G = floor_pow2(NT/ncell) lanes per cell -> single pass over all
// cells; two-pass LSE (max pass, then exp-sum pass) to avoid the online-LSE
// serial exp chain. softplus(rules) precomputed into global (L2) in prologue.

#define SS 192
#define LD 193
#define BB 16
#define NT 1024

__device__ __forceinline__ float softplusf(float x) {
  return fmaxf(x, 0.f) + log1pf(__expf(-fabsf(x)));
}

__global__ __launch_bounds__(NT) void cky_inside(const float* __restrict__ rules,
                                                 const int* __restrict__ lens,
                                                 float* __restrict__ chartG,
                                                 float* __restrict__ chartT,
                                                 float* __restrict__ spG,
                                                 float* __restrict__ outZ) {
  extern __shared__ float ch[];            // ch[i*LD + j]
  const int b = blockIdx.x;
  const int tid = threadIdx.x;
  const float* __restrict__ R = rules + (size_t)b * SS * SS;
  float* __restrict__ SPb = spG + (size_t)b * SS * SS;

  // prologue: softplus of the whole matrix -> global; diagonal -> LDS chart
  for (int idx = tid; idx < SS * SS; idx += NT) {
    float sp = softplusf(R[idx]);
    SPb[idx] = sp;
    int i = idx / SS;
    if (idx == i * SS + i) ch[i * LD + i] = sp;
  }
  __syncthreads();

  for (int w = 1; w < SS; ++w) {
    const int ncell = SS - w;
    int Glog = 31 - __clz(NT / ncell);     // floor log2; >=2 for ncell<=191
    if (Glog > 6) Glog = 6;
    const int G = 1 << Glog;
    const int c = tid >> Glog;             // ngrp = NT>>Glog >= ncell: one pass
    const int lane = tid & (G - 1);
    if (c < ncell) {
      const int i = c, j = c + w;
      const float sp = SPb[i * SS + j];    // prefetch (L2), off critical path
      // pass 1: max
      float m = -1e30f;
      for (int k = i + lane; k < j; k += G)
        m = fmaxf(m, ch[i * LD + k] + ch[(k + 1) * LD + j]);
      for (int off = G >> 1; off; off >>= 1)
        m = fmaxf(m, __shfl_xor(m, off));
      // pass 2: sum of exp (independent exps, add-chain only)
      float s = 0.f;
      for (int k = i + lane; k < j; k += G)
        s += __expf(ch[i * LD + k] + ch[(k + 1) * LD + j] - m);
      for (int off = G >> 1; off; off >>= 1)
        s += __shfl_xor(s, off);
      if (lane == 0)
        ch[i * LD + j] = sp + m + __logf(s);
    }
    __syncthreads();
  }

  // dump chart (+ transpose) for the outside pass; write Z
  float* __restrict__ Cb = chartG + (size_t)b * SS * SS;
  float* __restrict__ Tb = chartT + (size_t)b * SS * SS;
  for (int idx = tid; idx < SS * SS; idx += NT) {
    int i = idx / SS, j = idx - i * SS;
    float v = ch[i * LD + j];
    Cb[idx] = v;
    Tb[j * SS + i] = v;
  }
  if (tid == 0) {
    int L = lens[b];
    outZ[b] = ch[(L - 1)];                 // ch[0*LD + (L-1)]
  }
}

__global__ __launch_bounds__(NT) void cky_outside(const float* __restrict__ rules,
                                                  const int* __restrict__ lens,
                                                  const float* __restrict__ chartG,
                                                  const float* __restrict__ chartT,
                                                  const float* __restrict__ spG,
                                                  float* __restrict__ marg) {
  extern __shared__ float od[];            // od[i*LD + j] stores (outside + sp)
  const int b = blockIdx.x;
  const int tid = threadIdx.x;
  const int L = lens[b];
  const float* __restrict__ R  = rules  + (size_t)b * SS * SS;
  const float* __restrict__ C  = chartG + (size_t)b * SS * SS;
  const float* __restrict__ CT = chartT + (size_t)b * SS * SS;
  const float* __restrict__ SPb = spG   + (size_t)b * SS * SS;

  if (tid == 0) od[(L - 1)] = SPb[L - 1];  // root: o=0 -> store sp[0][L-1]
  __syncthreads();

  for (int w = L - 2; w >= 0; --w) {
    const int ncell = L - w;
    int Glog = 31 - __clz(NT / ncell);
    if (Glog > 6) Glog = 6;
    const int G = 1 << Glog;
    const int c = tid >> Glog;
    const int lane = tid & (G - 1);
    if (c < ncell) {
      const int i = c, j = c + w;
      const float sp = SPb[i * SS + j];    // prefetch
      // pass 1: max over both parent classes (uniform loops, no branch)
      float m = -1e30f;
      for (int p = j + 1 + lane; p < L; p += G)        // parent [i,p], left child
        m = fmaxf(m, od[i * LD + p] + C[(j + 1) * SS + p]);
      for (int a = lane; a < i; a += G)                // parent [a,j], right child
        m = fmaxf(m, od[a * LD + j] + CT[(i - 1) * SS + a]);
      for (int off = G >> 1; off; off >>= 1)
        m = fmaxf(m, __shfl_xor(m, off));
      // pass 2: sum of exp
      float s = 0.f;
      for (int p = j + 1 + lane; p < L; p += G)
        s += __expf(od[i * LD + p] + C[(j + 1) * SS + p] - m);
      for (int a = lane; a < i; a += G)
        s += __expf(od[a * LD + j] + CT[(i - 1) * SS + a] - m);
      for (int off = G >> 1; off; off >>= 1)
        s += __shfl_xor(s, off);
      if (lane == 0)
        od[i * LD + j] = sp + m + __logf(s);
    }
    __syncthreads();
  }

  // marginals
  const float Z = C[L - 1];                // c[0][L-1]
  float* __restrict__ Mb = marg + (size_t)b * SS * SS;
  for (int idx = tid; idx < SS * SS; idx += NT) {
    int i = idx / SS, j = idx - i * SS;
    float val = 0.f;
    if (i <= j && j < L) {
      float o = od[i * LD + j] - SPb[idx];
      float r = R[idx];
      float sig = 1.f / (1.f + __expf(-r));
      val = sig * __expf(o + C[idx] - Z);
    }
    Mb[idx] = val;
  }
}

extern "C" void kernel_launch(void* const* d_in, const int* in_sizes, int n_in,
                              void* d_out, int out_size, void* d_ws, size_t ws_size,
                              hipStream_t stream) {
  const float* rules = (const float*)d_in[0];   // (B,S,S,1) f32
  const int* lens = (const int*)d_in[1];        // (B,) i32
  float* outZ = (float*)d_out;                  // [0:16) = Z
  float* marg = (float*)d_out + BB;             // [16:) = marginal

  float* chartG = (float*)d_ws;                                   // B*S*S
  float* chartT = chartG + (size_t)BB * SS * SS;                  // B*S*S
  float* spG    = chartT + (size_t)BB * SS * SS;                  // B*S*S

  const int smem = SS * LD * sizeof(float);     // 148224 B
  hipFuncSetAttribute(reinterpret_cast<const void*>(cky_inside),
                      hipFuncAttributeMaxDynamicSharedMemorySize, smem);
  hipFuncSetAttribute(reinterpret_cast<const void*>(cky_outside),
                      hipFuncAttributeMaxDynamicSharedMemorySize, smem);

  cky_inside<<<BB, NT, smem, stream>>>(rules, lens, chartG, chartT, spG, outZ);
  cky_outside<<<BB, NT, smem, stream>>>(rules, lens, chartG, chartT, spG, marg);
}